// Round 17
// baseline (106.841 us; speedup 1.0000x reference)
//
#include <hip/hip_runtime.h>
#include <hip/hip_bf16.h>

#define BB 128
#define NN 1152
#define KD 512
#define NC 10
#define ND 16
#define CD 160   // NC*ND

typedef unsigned short ushort_t;
typedef unsigned int uint_t;
typedef short short8v __attribute__((ext_vector_type(8)));
typedef float float4v __attribute__((ext_vector_type(4)));
typedef float float16v __attribute__((ext_vector_type(16)));
typedef uint_t uint4v __attribute__((ext_vector_type(4)));

__device__ __forceinline__ float bf2f(ushort_t u) {
  return __uint_as_float(((uint_t)u) << 16);
}
// native RNE conversions (compiler emits v_cvt_pk_bf16_f32 pairs)
__device__ __forceinline__ ushort_t f2bf(float f) {
  __hip_bfloat16 h = __float2bfloat16(f);
  union { __hip_bfloat16 h; ushort_t u; } cv; cv.h = h; return cv.u;
}
__device__ __forceinline__ uint_t pk2(float a, float b) {
  float2 f; f.x = a; f.y = b;
  __hip_bfloat162 h = __float22bfloat162_rn(f);
  union { __hip_bfloat162 h; uint_t u; } cv; cv.h = h; return cv.u;
}

// Barrier that does NOT drain vmcnt: LDS-visibility (lgkmcnt) only.
#define BAR_LDS() do {                                   \
    __builtin_amdgcn_sched_barrier(0);                   \
    asm volatile("s_waitcnt lgkmcnt(0)" ::: "memory");   \
    __builtin_amdgcn_s_barrier();                        \
    __builtin_amdgcn_sched_barrier(0);                   \
  } while (0)

// ---------- W transpose+convert: Wt[n][k] = bf16(W[k][n]), [160][512] ----------
__global__ __launch_bounds__(256) void wconv(const float* __restrict__ W,
                                             ushort_t* __restrict__ Wt) {
  int idx = blockIdx.x * 256 + threadIdx.x;   // 81920 total
  int n = idx >> 9, k = idx & 511;
  Wt[idx] = f2bf(W[(size_t)k * CD + n]);
}

// ---------- GEMM 32x32x16: BM=128, BK=64, DEPTH-3 register prefetch ----------
// r14/r16 geometry (best measured) with prefetch slack doubled: tile n lives
// in register set n&1; at step ks we WRITE tile ks+1 (loaded 2 steps ago) and
// LOAD tile ks+3 -> each load batch has 2 full steps to land (Little's law:
// blocks stop stalling on their own load front; effective mem rate rises).
// Fully-unrolled 8-step loop -> all buffer/set selects compile-time (rule #20).
// ONE lgkmcnt-only barrier/step; vmcnt never drained at barriers.
// LDS: A[p]@p*16384 (16KB), B[p]@32768+p*20480 (20KB). 73728 B -> 2 blocks/CU.
// Swizzle slot ^= (row&7). Epilogue: Ct[128][168]@0 union + sAf@43008.
__global__ __launch_bounds__(256, 2) void gemm_mfma(
    const float* __restrict__ x, const ushort_t* __restrict__ Wt,
    ushort_t* __restrict__ uhat, float* __restrict__ partials) {
  __shared__ __align__(16) char smem[73728];
  const int tid = threadIdx.x;
  const int wid = tid >> 6, lane = tid & 63;
  const int l31 = lane & 31, lh = lane >> 5;
  // XCD-aware bijective swizzle: 1152 = 8 * 144 (contiguous chunk per XCD)
  const int bid = blockIdx.x;
  const int swz = (bid & 7) * 144 + (bid >> 3);
  const int row0 = swz * 128;

  float16v acc[5];
#pragma unroll
  for (int nt = 0; nt < 5; ++nt)
#pragma unroll
    for (int r = 0; r < 16; ++r) acc[nt][r] = 0.f;

  // A staging: 4 pieces f = tid + i*256 in [0,1024): row = f>>3 (0..127), slot = f&7
  int aby[4];
#pragma unroll
  for (int i = 0; i < 4; ++i) {
    int f = tid + i * 256;
    int ar = f >> 3, s = f & 7;
    aby[i] = (ar << 7) + ((s ^ (ar & 7)) << 4);
  }
  const int arow_ = tid >> 3;            // row of piece 0 (rows advance by 32/piece)
  const int akq = tid & 7;
  // B staging: 5 pieces f = tid + i*256 in [0,1280): row = f>>3 (0..159), slot = f&7
  int bsrc[5], bby[5];
#pragma unroll
  for (int i = 0; i < 5; ++i) {
    int f = tid + i * 256;
    int br = f >> 3, bs = f & 7;
    bsrc[i] = br * KD + bs * 8;
    bby[i] = (br << 7) + ((bs ^ (br & 7)) << 4);
  }

  // Two named register sets (tile n -> set n&1); no runtime indexing.
  float4v rA0[4][2], rA1[4][2];
  short8v rB0[5], rB1[5];

  auto LOADS0 = [&](int ks) {
    int k0 = ks * 64;
#pragma unroll
    for (int i = 0; i < 4; ++i) {
      const float* p = x + (size_t)(row0 + arow_ + i * 32) * KD + k0 + akq * 8;
      rA0[i][0] = *reinterpret_cast<const float4v*>(p);
      rA0[i][1] = *reinterpret_cast<const float4v*>(p + 4);
    }
#pragma unroll
    for (int i = 0; i < 5; ++i)
      rB0[i] = *reinterpret_cast<const short8v*>(Wt + bsrc[i] + k0);
  };
  auto LOADS1 = [&](int ks) {
    int k0 = ks * 64;
#pragma unroll
    for (int i = 0; i < 4; ++i) {
      const float* p = x + (size_t)(row0 + arow_ + i * 32) * KD + k0 + akq * 8;
      rA1[i][0] = *reinterpret_cast<const float4v*>(p);
      rA1[i][1] = *reinterpret_cast<const float4v*>(p + 4);
    }
#pragma unroll
    for (int i = 0; i < 5; ++i)
      rB1[i] = *reinterpret_cast<const short8v*>(Wt + bsrc[i] + k0);
  };
  auto WRITES0 = [&](int buf) {
    char* Ab = smem + buf * 16384;
    char* Bb = smem + 32768 + buf * 20480;
#pragma unroll
    for (int i = 0; i < 4; ++i) {
      uint4v p;
      p[0] = pk2(rA0[i][0][0], rA0[i][0][1]);
      p[1] = pk2(rA0[i][0][2], rA0[i][0][3]);
      p[2] = pk2(rA0[i][1][0], rA0[i][1][1]);
      p[3] = pk2(rA0[i][1][2], rA0[i][1][3]);
      *reinterpret_cast<uint4v*>(Ab + aby[i]) = p;
    }
#pragma unroll
    for (int i = 0; i < 5; ++i)
      *reinterpret_cast<short8v*>(Bb + bby[i]) = rB0[i];
  };
  auto WRITES1 = [&](int buf) {
    char* Ab = smem + buf * 16384;
    char* Bb = smem + 32768 + buf * 20480;
#pragma unroll
    for (int i = 0; i < 4; ++i) {
      uint4v p;
      p[0] = pk2(rA1[i][0][0], rA1[i][0][1]);
      p[1] = pk2(rA1[i][0][2], rA1[i][0][3]);
      p[2] = pk2(rA1[i][1][0], rA1[i][1][1]);
      p[3] = pk2(rA1[i][1][2], rA1[i][1][3]);
      *reinterpret_cast<uint4v*>(Ab + aby[i]) = p;
    }
#pragma unroll
    for (int i = 0; i < 5; ++i)
      *reinterpret_cast<short8v*>(Bb + bby[i]) = rB1[i];
  };

  const int arow = wid * 32 + l31;       // this lane's A row
  const int arx = arow & 7;

  // Prologue: tile0 staged; tiles 1,2 in flight (sets 1,0)
  LOADS0(0);
  WRITES0(0);
  LOADS1(1);
  LOADS0(2);
  BAR_LDS();                             // tile 0 visible

#pragma unroll
  for (int ks = 0; ks < 8; ++ks) {
    const char* Ab = smem + (ks & 1) * 16384;
    const char* Bb = smem + 32768 + (ks & 1) * 20480;
    __builtin_amdgcn_s_setprio(1);
#pragma unroll
    for (int ss = 0; ss < 4; ++ss) {     // K=16 sub-steps of BK=64
      int slot = ss * 2 + lh;
      short8v a = *reinterpret_cast<const short8v*>(
          Ab + (arow << 7) + ((slot ^ arx) << 4));
#pragma unroll
      for (int nt = 0; nt < 5; ++nt) {
        int brow = nt * 32 + l31;
        short8v bfr = *reinterpret_cast<const short8v*>(
            Bb + (brow << 7) + ((slot ^ (brow & 7)) << 4));
        acc[nt] = __builtin_amdgcn_mfma_f32_32x32x16_bf16(a, bfr, acc[nt], 0, 0, 0);
      }
    }
    __builtin_amdgcn_s_setprio(0);
    if (ks < 7) {                        // write tile ks+1 (set (ks+1)&1)
      if ((ks + 1) & 1) WRITES1((ks + 1) & 1);
      else              WRITES0((ks + 1) & 1);
    }
    if (ks < 5) {                        // load tile ks+3 into set (ks+3)&1
      if ((ks + 3) & 1) LOADS1(ks + 3);
      else              LOADS0(ks + 3);
    }
    BAR_LDS();
  }

  // ---- passA partials: col-sums over this block's 128 rows
  float* sAf = reinterpret_cast<float*>(smem + 43008);   // [4][160] = 2560 B
#pragma unroll
  for (int nt = 0; nt < 5; ++nt) {
    float p = 0.f;
#pragma unroll
    for (int r = 0; r < 16; ++r) p += acc[nt][r];
    p += __shfl_xor(p, 32);              // combine the two 16-row halves
    if (lh == 0) sAf[wid * CD + nt * 32 + l31] = p;
  }

  // ---- C repack through LDS union -> coalesced 16B stores
  ushort_t* Ct = reinterpret_cast<ushort_t*>(smem);      // [128][168] = 43008 B
#pragma unroll
  for (int nt = 0; nt < 5; ++nt)
#pragma unroll
    for (int r = 0; r < 16; ++r) {
      int row = wid * 32 + (r & 3) + 8 * (r >> 2) + 4 * lh;
      Ct[row * 168 + nt * 32 + l31] = f2bf(acc[nt][r]);
    }
  __syncthreads();
  if (tid < CD) {
    float s = sAf[tid] + sAf[CD + tid] + sAf[2 * CD + tid] + sAf[3 * CD + tid];
    partials[(size_t)swz * CD + tid] = s;
  }
#pragma unroll
  for (int i = 0; i < 10; ++i) {
    int p = tid + i * 256;               // 2560 pieces of 16B
    int row = p / 20, c0 = (p % 20) * 8;
    *reinterpret_cast<short8v*>(&uhat[(size_t)(row0 + row) * CD + c0]) =
        *reinterpret_cast<const short8v*>(&Ct[row * 168 + c0]);
  }
}

// ---------- routing iteration with fused v-computation ----------
// vv = v0 = squash(0.1*sum(pg 9 chunks)); ITER2 adds v1 = squash(sum(p1)).
#define ITER_T 640
template <int ITER2>
__global__ __launch_bounds__(ITER_T) void iter_k(
    const ushort_t* __restrict__ uhat, const float* __restrict__ pg,
    const float* __restrict__ p1, float* __restrict__ pout) {
  __shared__ float bv[128][NC];        // 5120 B
  __shared__ float wv[128][NC];        // 5120 B
  __shared__ float sred[32][CD];       // 20480 B
  __shared__ float sred2[4][CD];       // 2560 B
  __shared__ float vv[CD];             // 640 B
  const int blk = blockIdx.x;
  const int b = blk / 9, ch = blk % 9;
  const int t = threadIdx.x;
  const int g = t / 20, q = t % 20;
  const int c = q >> 1;
  const ushort_t* ub = uhat + ((size_t)b * NN + ch * 128) * CD + q * 8;

  // ---- prologue: compute vv (= v0, or v0+v1 for ITER2)
  if (t < CD) {
    float s0 = 0.f;
#pragma unroll
    for (int cc = 0; cc < 9; ++cc) s0 += pg[((size_t)b * 9 + cc) * CD + t];
    s0 *= 0.1f;
    float ss = s0 * s0;
    ss += __shfl_xor(ss, 1); ss += __shfl_xor(ss, 2);
    ss += __shfl_xor(ss, 4); ss += __shfl_xor(ss, 8);
    float sn = sqrtf(ss) + 1e-7f;
    float v = s0 * sn / (1.f + sn * sn);
    if (ITER2) {
      float s1 = 0.f;
#pragma unroll
      for (int cc = 0; cc < 9; ++cc) s1 += p1[((size_t)b * 9 + cc) * CD + t];
      float ss1 = s1 * s1;
      ss1 += __shfl_xor(ss1, 1); ss1 += __shfl_xor(ss1, 2);
      ss1 += __shfl_xor(ss1, 4); ss1 += __shfl_xor(ss1, 8);
      float sn1 = sqrtf(ss1) + 1e-7f;
      v += s1 * sn1 / (1.f + sn1 * sn1);
    }
    vv[t] = v;
  }
  __syncthreads();

  float v0r[8];
  {
    float4v a = *reinterpret_cast<const float4v*>(&vv[q * 8]);
    float4v bb = *reinterpret_cast<const float4v*>(&vv[q * 8 + 4]);
#pragma unroll
    for (int e = 0; e < 4; ++e) { v0r[e] = a[e]; v0r[e + 4] = bb[e]; }
  }

  // ---- phase 1: logits
  short8v u8[4];
#pragma unroll
  for (int it = 0; it < 4; ++it) {
    int n = g + it * 32;
    u8[it] = *reinterpret_cast<const short8v*>(ub + (size_t)n * CD);
    float p = 0.f;
#pragma unroll
    for (int e = 0; e < 8; ++e) p += bf2f((ushort_t)u8[it][e]) * v0r[e];
    p += __shfl_xor(p, 1);
    if ((q & 1) == 0) bv[n][c] = p;
  }
  __syncthreads();

  // ---- phase 1.5: softmax weights once per row
  if (t < 128) {
    float e[NC];
    float bm = bv[t][0];
#pragma unroll
    for (int cc = 1; cc < NC; ++cc) bm = fmaxf(bm, bv[t][cc]);
    float Z = 0.f;
#pragma unroll
    for (int cc = 0; cc < NC; ++cc) { e[cc] = __expf(bv[t][cc] - bm); Z += e[cc]; }
    float rz = 1.f / Z;
#pragma unroll
    for (int cc = 0; cc < NC; ++cc) wv[t][cc] = e[cc] * rz;
  }
  __syncthreads();

  // ---- phase 2: weighted accumulate
  float a[8];
#pragma unroll
  for (int e = 0; e < 8; ++e) a[e] = 0.f;
#pragma unroll
  for (int it = 0; it < 4; ++it) {
    int n = g + it * 32;
    float w = wv[n][c];
#pragma unroll
    for (int e = 0; e < 8; ++e) a[e] += w * bf2f((ushort_t)u8[it][e]);
  }
  {
    float4v lo, hi;
#pragma unroll
    for (int e = 0; e < 4; ++e) { lo[e] = a[e]; hi[e] = a[e + 4]; }
    float4v* dst = reinterpret_cast<float4v*>(&sred[g][q * 8]);
    dst[0] = lo; dst[1] = hi;
  }
  __syncthreads();
  {
    int col = t % CD, part = t / CD;    // 640 = 4 x 160
    float s = 0.f;
#pragma unroll
    for (int g8 = 0; g8 < 8; ++g8) s += sred[part * 8 + g8][col];
    sred2[part][col] = s;
  }
  __syncthreads();
  if (t < CD) {
    pout[(size_t)blk * CD + t] =
        sred2[0][t] + sred2[1][t] + sred2[2][t] + sred2[3][t];
  }
}

// ---------- final squash ----------
__global__ __launch_bounds__(CD) void squash_out(
    const float* __restrict__ p2, float* __restrict__ outp) {
  int b = blockIdx.x, t = threadIdx.x;
  float s = 0.f;
#pragma unroll
  for (int cc = 0; cc < 9; ++cc) s += p2[((size_t)b * 9 + cc) * CD + t];
  float ss = s * s;
  ss += __shfl_xor(ss, 1); ss += __shfl_xor(ss, 2);
  ss += __shfl_xor(ss, 4); ss += __shfl_xor(ss, 8);
  float sn = sqrtf(ss) + 1e-7f;
  outp[(size_t)b * CD + t] = s * sn / (1.f + sn * sn);
}

extern "C" void kernel_launch(void* const* d_in, const int* in_sizes, int n_in,
                              void* d_out, int out_size, void* d_ws, size_t ws_size,
                              hipStream_t stream) {
  const float* x = (const float*)d_in[0];   // [128,1152,512] f32
  const float* W = (const float*)d_in[1];   // [512,160] f32
  float* out = (float*)d_out;               // [128,10,16] f32

  char* ws = (char*)d_ws;
  ushort_t* uhat = (ushort_t*)ws;                          // 47,185,920 B
  ushort_t* Wt   = (ushort_t*)(ws + 47185920);             //    163,840 B
  float*    pg   = (float*)(ws + 47349760);                //    737,280 B  [1152][160]
  float*    p1   = (float*)(ws + 48087040);                //    737,280 B
  float*    p2   = (float*)(ws + 48824320);                //    737,280 B

  wconv<<<320, 256, 0, stream>>>(W, Wt);
  gemm_mfma<<<1152, 256, 0, stream>>>(x, Wt, uhat, pg);
  iter_k<0><<<1152, ITER_T, 0, stream>>>(uhat, pg, nullptr, p1);  // s1 partials
  iter_k<1><<<1152, ITER_T, 0, stream>>>(uhat, pg, p1, p2);       // s2 partials
  squash_out<<<BB, CD, 0, stream>>>(p2, out);                     // out = v2
}

// Round 18
// 103.446 us; speedup vs baseline: 1.0328x; 1.0328x over previous
//
#include <hip/hip_runtime.h>
#include <hip/hip_bf16.h>

#define BB 128
#define NN 1152
#define KD 512
#define NC 10
#define ND 16
#define CD 160   // NC*ND

typedef unsigned short ushort_t;
typedef unsigned int uint_t;
typedef short short8v __attribute__((ext_vector_type(8)));
typedef float float4v __attribute__((ext_vector_type(4)));
typedef float float16v __attribute__((ext_vector_type(16)));
typedef uint_t uint4v __attribute__((ext_vector_type(4)));

__device__ __forceinline__ float bf2f(ushort_t u) {
  return __uint_as_float(((uint_t)u) << 16);
}
// native RNE conversions (compiler emits v_cvt_pk_bf16_f32 pairs)
__device__ __forceinline__ ushort_t f2bf(float f) {
  __hip_bfloat16 h = __float2bfloat16(f);
  union { __hip_bfloat16 h; ushort_t u; } cv; cv.h = h; return cv.u;
}
__device__ __forceinline__ uint_t pk2(float a, float b) {
  float2 f; f.x = a; f.y = b;
  __hip_bfloat162 h = __float22bfloat162_rn(f);
  union { __hip_bfloat162 h; uint_t u; } cv; cv.h = h; return cv.u;
}

// Barrier that does NOT drain vmcnt: LDS-visibility (lgkmcnt) only.
#define BAR_LDS() do {                                   \
    __builtin_amdgcn_sched_barrier(0);                   \
    asm volatile("s_waitcnt lgkmcnt(0)" ::: "memory");   \
    __builtin_amdgcn_s_barrier();                        \
    __builtin_amdgcn_sched_barrier(0);                   \
  } while (0)

// ---------- W transpose+convert: Wt[n][k] = bf16(W[k][n]), [160][512] ----------
__global__ __launch_bounds__(256) void wconv(const float* __restrict__ W,
                                             ushort_t* __restrict__ Wt) {
  int idx = blockIdx.x * 256 + threadIdx.x;   // 81920 total
  int n = idx >> 9, k = idx & 511;
  Wt[idx] = f2bf(W[(size_t)k * CD + n]);
}

// ---------- GEMM via 32x32x16 MFMA: BM=128, BK=64, 256 thr (4 waves) ----------
// Best-measured configuration (r14: 103.1 us total, gemm ~79 us).
// Wave w = rows w*32..+32, all 160 cols (acc[5] f32x16). Grid 1152 = 8 XCD x 144.
// 8 k-steps, ONE lgkmcnt-only barrier/step, vmcnt never drained, depth-2
// register prefetch. Rows 128B, swizzle slot ^= (row&7).
// LDS: A[buf]@buf*16384 (16KB), B[buf]@32768+buf*20480 (20KB), sAf@43008.
// Total 73728 -> 2 blocks/CU. Epilogue Ct[128][168]@0 union.
__global__ __launch_bounds__(256, 2) void gemm_mfma(
    const float* __restrict__ x, const ushort_t* __restrict__ Wt,
    ushort_t* __restrict__ uhat, float* __restrict__ partials) {
  __shared__ __align__(16) char smem[73728];
  const int tid = threadIdx.x;
  const int wid = tid >> 6, lane = tid & 63;
  const int l31 = lane & 31, lh = lane >> 5;
  // XCD-aware bijective swizzle: 1152 = 8 * 144 (contiguous chunk per XCD)
  const int bid = blockIdx.x;
  const int swz = (bid & 7) * 144 + (bid >> 3);
  const int row0 = swz * 128;

  float16v acc[5];
#pragma unroll
  for (int nt = 0; nt < 5; ++nt)
#pragma unroll
    for (int r = 0; r < 16; ++r) acc[nt][r] = 0.f;

  // A staging: 4 pieces f = tid + i*256 in [0,1024): row = f>>3 (0..127), slot = f&7
  int aby[4];
#pragma unroll
  for (int i = 0; i < 4; ++i) {
    int f = tid + i * 256;
    int ar = f >> 3, s = f & 7;
    aby[i] = (ar << 7) + ((s ^ (ar & 7)) << 4);
  }
  const int arow_ = tid >> 3;            // row of piece 0 (rows advance by 32/piece)
  const int akq = tid & 7;
  // B staging: 5 pieces f = tid + i*256 in [0,1280): row = f>>3 (0..159), slot = f&7
  int bsrc[5], bby[5];
#pragma unroll
  for (int i = 0; i < 5; ++i) {
    int f = tid + i * 256;
    int br = f >> 3, bs = f & 7;
    bsrc[i] = br * KD + bs * 8;
    bby[i] = (br << 7) + ((bs ^ (br & 7)) << 4);
  }

  float4v rA[4][2];
  short8v rB[5];

  auto LOADS = [&](int ks) {
    int k0 = ks * 64;
#pragma unroll
    for (int i = 0; i < 4; ++i) {
      const float* p = x + (size_t)(row0 + arow_ + i * 32) * KD + k0 + akq * 8;
      rA[i][0] = *reinterpret_cast<const float4v*>(p);
      rA[i][1] = *reinterpret_cast<const float4v*>(p + 4);
    }
#pragma unroll
    for (int i = 0; i < 5; ++i)
      rB[i] = *reinterpret_cast<const short8v*>(Wt + bsrc[i] + k0);
  };
  auto WRITES = [&](int buf) {
    char* Ab = smem + buf * 16384;
    char* Bb = smem + 32768 + buf * 20480;
#pragma unroll
    for (int i = 0; i < 4; ++i) {
      uint4v p;
      p[0] = pk2(rA[i][0][0], rA[i][0][1]);
      p[1] = pk2(rA[i][0][2], rA[i][0][3]);
      p[2] = pk2(rA[i][1][0], rA[i][1][1]);
      p[3] = pk2(rA[i][1][2], rA[i][1][3]);
      *reinterpret_cast<uint4v*>(Ab + aby[i]) = p;
    }
#pragma unroll
    for (int i = 0; i < 5; ++i)
      *reinterpret_cast<short8v*>(Bb + bby[i]) = rB[i];
  };

  const int arow = wid * 32 + l31;       // this lane's A row
  const int arx = arow & 7;
  LOADS(0);
  WRITES(0);
  LOADS(1);
  BAR_LDS();                             // tile 0 visible
  int cur = 0;
  for (int ks = 0; ks < 8; ++ks) {
    const char* Ab = smem + cur * 16384;
    const char* Bb = smem + 32768 + cur * 20480;
#pragma unroll
    for (int ss = 0; ss < 4; ++ss) {     // K=16 sub-steps of BK=64
      int slot = ss * 2 + lh;
      short8v a = *reinterpret_cast<const short8v*>(
          Ab + (arow << 7) + ((slot ^ arx) << 4));
#pragma unroll
      for (int nt = 0; nt < 5; ++nt) {
        int brow = nt * 32 + l31;
        short8v bfr = *reinterpret_cast<const short8v*>(
            Bb + (brow << 7) + ((slot ^ (brow & 7)) << 4));
        acc[nt] = __builtin_amdgcn_mfma_f32_32x32x16_bf16(a, bfr, acc[nt], 0, 0, 0);
      }
    }
    if (ks < 7) {
      WRITES(cur ^ 1);                   // tile ks+1 -> other buf
      if (ks < 6) LOADS(ks + 2);
    }
    BAR_LDS();
    cur ^= 1;
  }

  // ---- passA partials: col-sums over this block's 128 rows
  float* sAf = reinterpret_cast<float*>(smem + 43008);   // [4][160] = 2560 B
#pragma unroll
  for (int nt = 0; nt < 5; ++nt) {
    float p = 0.f;
#pragma unroll
    for (int r = 0; r < 16; ++r) p += acc[nt][r];
    p += __shfl_xor(p, 32);              // combine the two 16-row halves
    if (lh == 0) sAf[wid * CD + nt * 32 + l31] = p;
  }

  // ---- C repack through LDS union -> coalesced 16B stores
  ushort_t* Ct = reinterpret_cast<ushort_t*>(smem);      // [128][168] = 43008 B
#pragma unroll
  for (int nt = 0; nt < 5; ++nt)
#pragma unroll
    for (int r = 0; r < 16; ++r) {
      int row = wid * 32 + (r & 3) + 8 * (r >> 2) + 4 * lh;
      Ct[row * 168 + nt * 32 + l31] = f2bf(acc[nt][r]);
    }
  __syncthreads();
  if (tid < CD) {
    float s = sAf[tid] + sAf[CD + tid] + sAf[2 * CD + tid] + sAf[3 * CD + tid];
    partials[(size_t)swz * CD + tid] = s;
  }
#pragma unroll
  for (int i = 0; i < 10; ++i) {
    int p = tid + i * 256;               // 2560 pieces of 16B
    int row = p / 20, c0 = (p % 20) * 8;
    *reinterpret_cast<short8v*>(&uhat[(size_t)(row0 + row) * CD + c0]) =
        *reinterpret_cast<const short8v*>(&Ct[row * 168 + c0]);
  }
}

// ---------- routing iteration with fused v-computation ----------
// vv = v0 = squash(0.1*sum(pg 9 chunks)); ITER2 adds v1 = squash(sum(p1)).
#define ITER_T 640
template <int ITER2>
__global__ __launch_bounds__(ITER_T) void iter_k(
    const ushort_t* __restrict__ uhat, const float* __restrict__ pg,
    const float* __restrict__ p1, float* __restrict__ pout) {
  __shared__ float bv[128][NC];        // 5120 B
  __shared__ float wv[128][NC];        // 5120 B
  __shared__ float sred[32][CD];       // 20480 B
  __shared__ float sred2[4][CD];       // 2560 B
  __shared__ float vv[CD];             // 640 B
  const int blk = blockIdx.x;
  const int b = blk / 9, ch = blk % 9;
  const int t = threadIdx.x;
  const int g = t / 20, q = t % 20;
  const int c = q >> 1;
  const ushort_t* ub = uhat + ((size_t)b * NN + ch * 128) * CD + q * 8;

  // ---- prologue: compute vv (= v0, or v0+v1 for ITER2)
  if (t < CD) {
    float s0 = 0.f;
#pragma unroll
    for (int cc = 0; cc < 9; ++cc) s0 += pg[((size_t)b * 9 + cc) * CD + t];
    s0 *= 0.1f;
    float ss = s0 * s0;
    ss += __shfl_xor(ss, 1); ss += __shfl_xor(ss, 2);
    ss += __shfl_xor(ss, 4); ss += __shfl_xor(ss, 8);
    float sn = sqrtf(ss) + 1e-7f;
    float v = s0 * sn / (1.f + sn * sn);
    if (ITER2) {
      float s1 = 0.f;
#pragma unroll
      for (int cc = 0; cc < 9; ++cc) s1 += p1[((size_t)b * 9 + cc) * CD + t];
      float ss1 = s1 * s1;
      ss1 += __shfl_xor(ss1, 1); ss1 += __shfl_xor(ss1, 2);
      ss1 += __shfl_xor(ss1, 4); ss1 += __shfl_xor(ss1, 8);
      float sn1 = sqrtf(ss1) + 1e-7f;
      v += s1 * sn1 / (1.f + sn1 * sn1);
    }
    vv[t] = v;
  }
  __syncthreads();

  float v0r[8];
  {
    float4v a = *reinterpret_cast<const float4v*>(&vv[q * 8]);
    float4v bb = *reinterpret_cast<const float4v*>(&vv[q * 8 + 4]);
#pragma unroll
    for (int e = 0; e < 4; ++e) { v0r[e] = a[e]; v0r[e + 4] = bb[e]; }
  }

  // ---- phase 1: logits
  short8v u8[4];
#pragma unroll
  for (int it = 0; it < 4; ++it) {
    int n = g + it * 32;
    u8[it] = *reinterpret_cast<const short8v*>(ub + (size_t)n * CD);
    float p = 0.f;
#pragma unroll
    for (int e = 0; e < 8; ++e) p += bf2f((ushort_t)u8[it][e]) * v0r[e];
    p += __shfl_xor(p, 1);
    if ((q & 1) == 0) bv[n][c] = p;
  }
  __syncthreads();

  // ---- phase 1.5: softmax weights once per row
  if (t < 128) {
    float e[NC];
    float bm = bv[t][0];
#pragma unroll
    for (int cc = 1; cc < NC; ++cc) bm = fmaxf(bm, bv[t][cc]);
    float Z = 0.f;
#pragma unroll
    for (int cc = 0; cc < NC; ++cc) { e[cc] = __expf(bv[t][cc] - bm); Z += e[cc]; }
    float rz = 1.f / Z;
#pragma unroll
    for (int cc = 0; cc < NC; ++cc) wv[t][cc] = e[cc] * rz;
  }
  __syncthreads();

  // ---- phase 2: weighted accumulate
  float a[8];
#pragma unroll
  for (int e = 0; e < 8; ++e) a[e] = 0.f;
#pragma unroll
  for (int it = 0; it < 4; ++it) {
    int n = g + it * 32;
    float w = wv[n][c];
#pragma unroll
    for (int e = 0; e < 8; ++e) a[e] += w * bf2f((ushort_t)u8[it][e]);
  }
  {
    float4v lo, hi;
#pragma unroll
    for (int e = 0; e < 4; ++e) { lo[e] = a[e]; hi[e] = a[e + 4]; }
    float4v* dst = reinterpret_cast<float4v*>(&sred[g][q * 8]);
    dst[0] = lo; dst[1] = hi;
  }
  __syncthreads();
  {
    int col = t % CD, part = t / CD;    // 640 = 4 x 160
    float s = 0.f;
#pragma unroll
    for (int g8 = 0; g8 < 8; ++g8) s += sred[part * 8 + g8][col];
    sred2[part][col] = s;
  }
  __syncthreads();
  if (t < CD) {
    pout[(size_t)blk * CD + t] =
        sred2[0][t] + sred2[1][t] + sred2[2][t] + sred2[3][t];
  }
}

// ---------- final squash ----------
__global__ __launch_bounds__(CD) void squash_out(
    const float* __restrict__ p2, float* __restrict__ outp) {
  int b = blockIdx.x, t = threadIdx.x;
  float s = 0.f;
#pragma unroll
  for (int cc = 0; cc < 9; ++cc) s += p2[((size_t)b * 9 + cc) * CD + t];
  float ss = s * s;
  ss += __shfl_xor(ss, 1); ss += __shfl_xor(ss, 2);
  ss += __shfl_xor(ss, 4); ss += __shfl_xor(ss, 8);
  float sn = sqrtf(ss) + 1e-7f;
  outp[(size_t)b * CD + t] = s * sn / (1.f + sn * sn);
}

extern "C" void kernel_launch(void* const* d_in, const int* in_sizes, int n_in,
                              void* d_out, int out_size, void* d_ws, size_t ws_size,
                              hipStream_t stream) {
  const float* x = (const float*)d_in[0];   // [128,1152,512] f32
  const float* W = (const float*)d_in[1];   // [512,160] f32
  float* out = (float*)d_out;               // [128,10,16] f32

  char* ws = (char*)d_ws;
  ushort_t* uhat = (ushort_t*)ws;                          // 47,185,920 B
  ushort_t* Wt   = (ushort_t*)(ws + 47185920);             //    163,840 B
  float*    pg   = (float*)(ws + 47349760);                //    737,280 B  [1152][160]
  float*    p1   = (float*)(ws + 48087040);                //    737,280 B
  float*    p2   = (float*)(ws + 48824320);                //    737,280 B

  wconv<<<320, 256, 0, stream>>>(W, Wt);
  gemm_mfma<<<1152, 256, 0, stream>>>(x, Wt, uhat, pg);
  iter_k<0><<<1152, ITER_T, 0, stream>>>(uhat, pg, nullptr, p1);  // s1 partials
  iter_k<1><<<1152, ITER_T, 0, stream>>>(uhat, pg, p1, p2);       // s2 partials
  squash_out<<<BB, CD, 0, stream>>>(p2, out);                     // out = v2
}